// Round 14
// baseline (390.347 us; speedup 1.0000x reference)
//
#include <hip/hip_runtime.h>
#include <hip/hip_bf16.h>
#include <stdint.h>

#define BATCH 128
#define SEQ   512
#define NW    6
#define DIM   64
#define NELEM (BATCH * SEQ * NW)   // 393216
#define PI_F  3.14159265358979323846f

typedef float v2f __attribute__((ext_vector_type(2)));

__device__ __forceinline__ v2f pkfma(float s, v2f m, v2f a) {
    return __builtin_elementwise_fma((v2f){s, s}, m, a);
}

// ---------------------------------------------------------------------------
// Interleaved 3-way DPP wave-64 reduction stage. After shr1,2,4,8 +
// bcast15,31 the totals land in lane 63.
// ---------------------------------------------------------------------------
template <int CTRL>
__device__ __forceinline__ void red_stage3(float v[3]) {
#pragma unroll
    for (int k = 0; k < 3; ++k)
        v[k] += __int_as_float(__builtin_amdgcn_update_dpp(
            0, __float_as_int(v[k]), CTRL, 0xF, 0xF, false));
}

// Branch-free sincos(h/2), |h| <= 1 (bf16-output tolerance).
__device__ __forceinline__ void sincos_half(float h, float& s, float& c) {
    const float u = h * h;
    c = fmaf(u, fmaf(u, 2.6041667e-3f, -0.125f), 1.0f);
    s = h * fmaf(u, fmaf(u, 2.6041667e-4f, -2.0833333e-2f), 0.5f);
}

__device__ __forceinline__ float ldf(const void* p, int i, bool bf) {
    if (bf) {
        uint32_t u = (uint32_t)((const uint16_t*)p)[i];
        return __uint_as_float(u << 16);
    }
    return ((const float*)p)[i];
}

// Per-block bf16-vs-f32 self-detection from the first 256 words of angles.
__device__ __forceinline__ bool detect_bf16(const void* ang, int* cnt) {
    if (threadIdx.x == 0) *cnt = 0;
    __syncthreads();
    uint32_t w = ((const uint32_t*)ang)[threadIdx.x & 255];
    uint32_t e = (w >> 8) & 0xFFu;
    if (e >= 0x3Au && e <= 0x41u) atomicAdd(cnt, 1);
    __syncthreads();
    return *cnt >= 128;
}

// ---------------------------------------------------------------------------
// Kernel 1: msetup only — 32 blocks x 256; each wave evolves one (dir,col)
// basis column of the step unitary -> Mg [dir][row][col][2]. Self-detects
// dtype; reads params straight from d_in. Runs once; perf-irrelevant.
// ---------------------------------------------------------------------------
__global__ void __launch_bounds__(256) k_msetup(const void* ang, const void* poly,
                                                const void* fp, const void* bp,
                                                float* __restrict__ Mg) {
    __shared__ int cnt;
    const bool bf = detect_bf16(ang, &cnt);

    const int lane = threadIdx.x & 63;
    const int tix  = blockIdx.x * 4 + (threadIdx.x >> 6);
    const int dir  = tix >> 6;
    const int col  = tix & 63;
    const void* prm = dir ? bp : fp;
    const int p = lane;

    float yr = (p == col) ? 1.f : 0.f;
    float yi = 0.f;

#pragma unroll
    for (int d = 0; d < 4; ++d) {
        const float th = 0.5f * PI_F * ldf(poly, d, bf) *
                         (float)(6 - 2 * (int)__popc((unsigned)p));
        float s, c;
        __sincosf(th, &s, &c);
        const float nr = yr * c + yi * s;
        const float ni = yi * c - yr * s;
        yr = nr; yi = ni;
#pragma unroll
        for (int k = 0; k < 6; ++k) {
            const int cw = k, tw = (k + 1) % 6;
            const int src = p ^ (((p >> (5 - cw)) & 1) << (5 - tw));
            yr = __shfl(yr, src, 64);
            yi = __shfl(yi, src, 64);
        }
    }

    int idx = 0;
#pragma unroll
    for (int l = 0; l < 2; ++l) {
#pragma unroll
        for (int w = 0; w < 6; ++w) {
            float cx, sx, cy, sy, cz, sz;
            __sincosf(0.5f * ldf(prm, idx + 0, bf), &sx, &cx);
            __sincosf(0.5f * ldf(prm, idx + 1, bf), &sy, &cy);
            __sincosf(0.5f * ldf(prm, idx + 2, bf), &sz, &cz);
            idx += 3;
            const float A = cy * cx, B = sy * sx, C = sy * cx, D = cy * sx;
            const float U00r = cz * A + sz * B, U00i = cz * B - sz * A;
            const float U11r = U00r,            U11i = sz * A - cz * B;
            const float Xr   = cz * C + sz * D, Xi   = sz * C - cz * D;
            const int m  = 1 << (5 - w);
            const int bb = (p >> (5 - w)) & 1;
            const float C1r = bb ? U11r : U00r;
            const float C1i = bb ? U11i : U00i;
            const float C2r = bb ? Xr : -Xr;
            const float C2i = Xi;
            const float pr = __shfl_xor(yr, m, 64);
            const float pi = __shfl_xor(yi, m, 64);
            const float nr = C1r * yr - C1i * yi + C2r * pr - C2i * pi;
            const float ni = C1r * yi + C1i * yr + C2r * pi + C2i * pr;
            yr = nr; yi = ni;
        }
#pragma unroll
        for (int k = 0; k < 5; ++k) {
            const int src = p ^ (((p >> (5 - k)) & 1) << (5 - (k + 1)));
            yr = __shfl(yr, src, 64);
            yi = __shfl(yi, src, 64);
        }
    }

    float* out = Mg + ((size_t)(dir * 64 + p) * 64 + (size_t)col) * 2;
    out[0] = yr;
    out[1] = yi;
}

// ---------------------------------------------------------------------------
// Kernel 2: recurrent sim — r13 structure (4 waves, split measurement, two
// barriers) with:
//  - fused angle conversion: this block's 3072 angles -> sincos -> cl
//    directly (no cs pass, no k_prep convert blocks)
//  - X-wave bpermutes replaced by ADDRESS-SHIFTED pY reads:
//    y[lane^m] = sum_wv pY[wv][lane^m] — partials at [lane] and [lane^m]
//    fetched in ONE batched LDS window (removes a serial ~120-cyc DS window
//    from the block-critical X-wave path).
// ---------------------------------------------------------------------------
__global__ void __launch_bounds__(256, 1) k_sim(const void* __restrict__ ang,
                                                const float* __restrict__ Mg,
                                                float* __restrict__ hbuf) {
    const int tid   = threadIdx.x;
    const int lane  = tid & 63;
    const int wv    = tid >> 6;              // wave 0..3
    const int chain = blockIdx.x;            // 0..255
    const int dir   = chain >> 7;
    const int b     = chain & 127;
    float* orow = hbuf + (size_t)dir * NELEM + (size_t)b * (SEQ * NW);

    __shared__ __align__(16) float  cl[SEQ * 12];   // 24 KB cos/sin(x)
    __shared__ __align__(16) float  zb[SEQ * NW];   // 12 KB output buffer
    __shared__ float2 pY[2][4][DIM];                // ping-pong partials, 4 KB
    __shared__ __align__(16) float  mR[12];         // measure-sum slab
    __shared__ int cnt;

    const bool bf = detect_bf16(ang, &cnt);

    // ---- convert this chain's 3072 angles -> cl (cos,sin interleaved) ----
    {
        const int abase = b * (SEQ * NW);
#pragma unroll
        for (int k = 0; k < 12; ++k) {
            const int i = tid + k * 256;
            const float x = ldf(ang, abase + i, bf);
            float s, c;
            __sincosf(x, &s, &c);
            cl[2 * i]     = c;
            cl[2 * i + 1] = s;
        }
    }

    // ---- my 16 resident M columns: row = lane, cols = 16wv..16wv+15 ----
    v2f Mres[16];
    {
        const float2* mr2 =
            (const float2*)(Mg + (size_t)(dir * 64 + lane) * 128 + 32 * wv);
#pragma unroll
        for (int k = 0; k < 16; ++k) Mres[k] = (v2f){mr2[k].x, mr2[k].y};
    }

    // ---- my measurement assignment: 3 wires, Z or X ----
    const int w0  = (wv & 1) * 3;            // wire base
    const int isX = wv >> 1;                 // waves 2,3 do <X>
    int zmask3[3], xadr[3];
#pragma unroll
    for (int k = 0; k < 3; ++k) {
        const int w = w0 + k;
        zmask3[k] = ((lane >> (5 - w)) & 1) << 31;
        xadr[k]   = lane ^ (1 << (5 - w));   // shifted pY read address
    }
    const int ow0 = wv ^ 1, ow1 = wv ^ 2, ow2 = wv ^ 3;   // other waves

    float h[6] = {0.f, 0.f, 0.f, 0.f, 0.f, 0.f};

    // encode h -> my 16-col matvec partial (registers only)
    auto encode_matvec = [&](v2f& acc) {
        float cw6[6], sw6[6];
#pragma unroll
        for (int w = 0; w < 6; ++w) sincos_half(h[w], sw6[w], cw6[w]);
        const float t0 = (wv & 2) ? sw6[0] : cw6[0];   // wire0 bit = wv>>1
        const float t1 = (wv & 1) ? sw6[1] : cw6[1];   // wire1 bit = wv&1
        const float A  = t0 * t1;
        float GH[4], GL[4];
        GH[0] = cw6[2] * cw6[3]; GH[1] = cw6[2] * sw6[3];
        GH[2] = sw6[2] * cw6[3]; GH[3] = sw6[2] * sw6[3];
#pragma unroll
        for (int a = 0; a < 4; ++a) GH[a] *= A;
        GL[0] = cw6[4] * cw6[5]; GL[1] = cw6[4] * sw6[5];
        GL[2] = sw6[4] * cw6[5]; GL[3] = sw6[4] * sw6[5];
        v2f y = {0.f, 0.f};
#pragma unroll
        for (int a = 0; a < 4; ++a) {
            v2f T = {0.f, 0.f};
#pragma unroll
            for (int b2 = 0; b2 < 4; ++b2)
                T = pkfma(GL[b2], Mres[4 * a + b2], T);
            y = pkfma(GH[a], T, y);
        }
        acc = y;
    };

    // walking pointers
    const float* cp = cl + (dir ? (SEQ - 1) * 12 : 0);
    const int   cstep = dir ? -12 : 12;
    float*       zp = zb + (dir ? (SEQ - 1) * NW : 0);
    const int   zstep = dir ? -NW : NW;

    __syncthreads();                         // cl staging + Mres visible

    // ---- peel: partial for the t=0 state (h = 0) ----
    v2f myacc;
    encode_matvec(myacc);
    pY[0][wv][lane] = (float2){myacc.x, myacc.y};
    __syncthreads();                         // barrier A

    for (int t = 0; t < SEQ; ++t) {
        const int buf = t & 1;

        // ONE batched LDS window: partner partials at [lane], this step's
        // cos/sin, and (X waves) all partials at the 3 shifted addresses.
        const float2 yA = pY[buf][ow0][lane];
        const float2 yB = pY[buf][ow1][lane];
        const float2 yC = pY[buf][ow2][lane];
        const float4 xq0 = ((const float4*)cp)[0];
        const float4 xq1 = ((const float4*)cp)[1];
        const float4 xq2 = ((const float4*)cp)[2];
        cp += cstep;

        float v3[3];
        if (isX) {
            float2 t0[3], t1[3], t2[3], t3[3];
#pragma unroll
            for (int k = 0; k < 3; ++k) {
                t0[k] = pY[buf][0][xadr[k]];
                t1[k] = pY[buf][1][xadr[k]];
                t2[k] = pY[buf][2][xadr[k]];
                t3[k] = pY[buf][3][xadr[k]];
            }
            const float yr = (myacc.x + yA.x) + (yB.x + yC.x);
            const float yi = (myacc.y + yA.y) + (yB.y + yC.y);
#pragma unroll
            for (int k = 0; k < 3; ++k) {
                const float yrm = (t0[k].x + t1[k].x) + (t2[k].x + t3[k].x);
                const float yim = (t0[k].y + t1[k].y) + (t2[k].y + t3[k].y);
                v3[k] = yr * yrm + yi * yim;
            }
        } else {
            const float yr = (myacc.x + yA.x) + (yB.x + yC.x);
            const float yi = (myacc.y + yA.y) + (yB.y + yC.y);
            const float q = yr * yr + yi * yi;
#pragma unroll
            for (int k = 0; k < 3; ++k)
                v3[k] = __int_as_float(__float_as_int(q) ^ zmask3[k]);
        }
        red_stage3<0x111>(v3);   // row_shr:1
        red_stage3<0x112>(v3);   // row_shr:2
        red_stage3<0x114>(v3);   // row_shr:4
        red_stage3<0x118>(v3);   // row_shr:8
        red_stage3<0x142>(v3);   // row_bcast:15
        red_stage3<0x143>(v3);   // row_bcast:31

        if (lane == 63) {
            mR[wv * 3 + 0] = v3[0];
            mR[wv * 3 + 1] = v3[1];
            mR[wv * 3 + 2] = v3[2];
        }
        __syncthreads();                     // barrier B

        // slab read is the only post-B LDS dependency
        const float4 m0 = ((const float4*)mR)[0];   // Z0 Z1 Z2 Z3
        const float4 m1 = ((const float4*)mR)[1];   // Z4 Z5 X0 X1
        const float4 m2 = ((const float4*)mR)[2];   // X2 X3 X4 X5

        float z[6];
        z[0] = xq0.x * m0.x - xq0.y * m1.z;
        z[1] = xq0.z * m0.y - xq0.w * m1.w;
        z[2] = xq1.x * m0.z - xq1.y * m2.x;
        z[3] = xq1.z * m0.w - xq1.w * m2.y;
        z[4] = xq2.x * m1.x - xq2.y * m2.z;
        z[5] = xq2.z * m1.y - xq2.w * m2.w;

        if (tid == 63) {                     // one lane buffers outputs
#pragma unroll
            for (int w = 0; w < 6; ++w) zp[w] = z[w];
        }
        zp += zstep;
#pragma unroll
        for (int w = 0; w < 6; ++w) h[w] = z[w];   // h stays in VGPRs

        // next state's partial into the other buffer
        encode_matvec(myacc);
        pY[buf ^ 1][wv][lane] = (float2){myacc.x, myacc.y};
        __syncthreads();                     // barrier A
    }

    // ---- bulk store outputs: 768 float4 over 256 threads ----
    {
        const float4* zs4 = (const float4*)zb;
        float4* go = (float4*)orow;
#pragma unroll
        for (int k = 0; k < 3; ++k) {
            const int idx = tid + k * 256;
            go[idx] = zs4[idx];
        }
    }
}

// ---------------------------------------------------------------------------
// Kernel 3: out = sigmoid(fc)*h_fwd + sigmoid(bc)*h_bwd. Self-detects dtype
// and reads fc/bc raw (no misc/flag dependency).
// ---------------------------------------------------------------------------
__global__ void k_combine(const float* __restrict__ hbuf,
                          const void* __restrict__ ang,
                          const void* __restrict__ fc,
                          const void* __restrict__ bc,
                          void* __restrict__ out) {
    __shared__ int cnt;
    const bool bf = detect_bf16(ang, &cnt);
    const int i = blockIdx.x * blockDim.x + threadIdx.x;   // grid == NELEM
    const float sf = 1.f / (1.f + __expf(-ldf(fc, 0, bf)));
    const float sb = 1.f / (1.f + __expf(-ldf(bc, 0, bf)));
    const float v = sf * hbuf[i] + sb * hbuf[NELEM + i];
    if (bf) ((__hip_bfloat16*)out)[i] = __float2bfloat16(v);
    else    ((float*)out)[i] = v;
}

// ---------------------------------------------------------------------------
extern "C" void kernel_launch(void* const* d_in, const int* in_sizes, int n_in,
                              void* d_out, int out_size, void* d_ws, size_t ws_size,
                              hipStream_t stream) {
    const void* ang  = d_in[0];
    const void* poly = d_in[1];
    const void* fp   = d_in[2];
    const void* bp   = d_in[3];
    const void* fc   = d_in[4];
    const void* bc   = d_in[5];

    // ws (floats): hbuf[2*NELEM] | Mg[16384]
    float* hbuf = (float*)d_ws;
    float* Mg   = hbuf + 2 * NELEM;

    k_msetup<<<32, 256, 0, stream>>>(ang, poly, fp, bp, Mg);
    k_sim<<<256, 256, 0, stream>>>(ang, Mg, hbuf);
    k_combine<<<NELEM / 256, 256, 0, stream>>>(hbuf, ang, fc, bc, d_out);
}

// Round 16
// 357.273 us; speedup vs baseline: 1.0926x; 1.0926x over previous
//
#include <hip/hip_runtime.h>
#include <hip/hip_bf16.h>
#include <stdint.h>

#define BATCH 128
#define SEQ   512
#define NW    6
#define DIM   64
#define NELEM (BATCH * SEQ * NW)   // 393216
#define PI_F  3.14159265358979323846f

typedef float v2f __attribute__((ext_vector_type(2)));

__device__ __forceinline__ v2f pkfma(float s, v2f m, v2f a) {
    return __builtin_elementwise_fma((v2f){s, s}, m, a);
}

// ---------------------------------------------------------------------------
// Interleaved 3-way DPP wave-64 reduction stage. After shr1,2,4,8 +
// bcast15,31 the totals land in lane 63.
// ---------------------------------------------------------------------------
template <int CTRL>
__device__ __forceinline__ void red_stage3(float v[3]) {
#pragma unroll
    for (int k = 0; k < 3; ++k)
        v[k] += __int_as_float(__builtin_amdgcn_update_dpp(
            0, __float_as_int(v[k]), CTRL, 0xF, 0xF, false));
}

// DPP / swizzle data movement — control code as template constant
// (the builtins require immediate operands).
template <int CTRL>
__device__ __forceinline__ float dpp_mov(float x) {
    return __int_as_float(__builtin_amdgcn_update_dpp(
        0, __float_as_int(x), CTRL, 0xF, 0xF, false));
}
template <int PAT>
__device__ __forceinline__ float swz(float x) {
    return __int_as_float(__builtin_amdgcn_ds_swizzle(__float_as_int(x), PAT));
}

// Branch-free sincos(h/2), |h| <= 1 (bf16-output tolerance).
__device__ __forceinline__ void sincos_half(float h, float& s, float& c) {
    const float u = h * h;
    c = fmaf(u, fmaf(u, 2.6041667e-3f, -0.125f), 1.0f);
    s = h * fmaf(u, fmaf(u, 2.6041667e-4f, -2.0833333e-2f), 0.5f);
}

__device__ __forceinline__ float ldf(const void* p, int i, bool bf) {
    if (bf) {
        uint32_t u = (uint32_t)((const uint16_t*)p)[i];
        return __uint_as_float(u << 16);
    }
    return ((const float*)p)[i];
}

// Per-block bf16-vs-f32 self-detection from the first 256 words of angles.
__device__ __forceinline__ bool detect_bf16(const void* ang, int* cnt) {
    if (threadIdx.x == 0) *cnt = 0;
    __syncthreads();
    uint32_t w = ((const uint32_t*)ang)[threadIdx.x & 255];
    uint32_t e = (w >> 8) & 0xFFu;
    if (e >= 0x3Au && e <= 0x41u) atomicAdd(cnt, 1);
    __syncthreads();
    return *cnt >= 128;
}

// ---------------------------------------------------------------------------
// Kernel 1: msetup — 32 blocks x 256; each wave evolves one (dir,col) basis
// column of the step unitary -> Mg [dir][row][col][2]. Runs once.
// ---------------------------------------------------------------------------
__global__ void __launch_bounds__(256) k_msetup(const void* ang, const void* poly,
                                                const void* fp, const void* bp,
                                                float* __restrict__ Mg) {
    __shared__ int cnt;
    const bool bf = detect_bf16(ang, &cnt);

    const int lane = threadIdx.x & 63;
    const int tix  = blockIdx.x * 4 + (threadIdx.x >> 6);
    const int dir  = tix >> 6;
    const int col  = tix & 63;
    const void* prm = dir ? bp : fp;
    const int p = lane;

    float yr = (p == col) ? 1.f : 0.f;
    float yi = 0.f;

#pragma unroll
    for (int d = 0; d < 4; ++d) {
        const float th = 0.5f * PI_F * ldf(poly, d, bf) *
                         (float)(6 - 2 * (int)__popc((unsigned)p));
        float s, c;
        __sincosf(th, &s, &c);
        const float nr = yr * c + yi * s;
        const float ni = yi * c - yr * s;
        yr = nr; yi = ni;
#pragma unroll
        for (int k = 0; k < 6; ++k) {
            const int cw = k, tw = (k + 1) % 6;
            const int src = p ^ (((p >> (5 - cw)) & 1) << (5 - tw));
            yr = __shfl(yr, src, 64);
            yi = __shfl(yi, src, 64);
        }
    }

    int idx = 0;
#pragma unroll
    for (int l = 0; l < 2; ++l) {
#pragma unroll
        for (int w = 0; w < 6; ++w) {
            float cx, sx, cy, sy, cz, sz;
            __sincosf(0.5f * ldf(prm, idx + 0, bf), &sx, &cx);
            __sincosf(0.5f * ldf(prm, idx + 1, bf), &sy, &cy);
            __sincosf(0.5f * ldf(prm, idx + 2, bf), &sz, &cz);
            idx += 3;
            const float A = cy * cx, B = sy * sx, C = sy * cx, D = cy * sx;
            const float U00r = cz * A + sz * B, U00i = cz * B - sz * A;
            const float U11r = U00r,            U11i = sz * A - cz * B;
            const float Xr   = cz * C + sz * D, Xi   = sz * C - cz * D;
            const int m  = 1 << (5 - w);
            const int bb = (p >> (5 - w)) & 1;
            const float C1r = bb ? U11r : U00r;
            const float C1i = bb ? U11i : U00i;
            const float C2r = bb ? Xr : -Xr;
            const float C2i = Xi;
            const float pr = __shfl_xor(yr, m, 64);
            const float pi = __shfl_xor(yi, m, 64);
            const float nr = C1r * yr - C1i * yi + C2r * pr - C2i * pi;
            const float ni = C1r * yi + C1i * yr + C2r * pi + C2i * pr;
            yr = nr; yi = ni;
        }
#pragma unroll
        for (int k = 0; k < 5; ++k) {
            const int src = p ^ (((p >> (5 - k)) & 1) << (5 - (k + 1)));
            yr = __shfl(yr, src, 64);
            yi = __shfl(yi, src, 64);
        }
    }

    float* out = Mg + ((size_t)(dir * 64 + p) * 64 + (size_t)col) * 2;
    out[0] = yr;
    out[1] = yi;
}

// ---------------------------------------------------------------------------
// Kernel 2: recurrent sim — r13 structure (4 waves, split measurement, two
// barriers, bpermute partner fetch) with the r14 fused angle conversion AND
// a cheaper X partner fetch:
//   wave2 (masks 32,16,8): bpermute / ds_swizzle XOR16 / DPP row_ror:8
//   wave3 (masks 4,2,1):   ds_swizzle XOR4 / DPP quad_perm XOR2 / XOR1
// X-wave DS ops in the measurement window: 6 -> 2 each (r14 lesson: the
// block's per-step DS-op total is a shared-pipe budget).
// ---------------------------------------------------------------------------
__global__ void __launch_bounds__(256, 1) k_sim(const void* __restrict__ ang,
                                                const float* __restrict__ Mg,
                                                float* __restrict__ hbuf) {
    const int tid   = threadIdx.x;
    const int lane  = tid & 63;
    const int wv    = tid >> 6;              // wave 0..3
    const int chain = blockIdx.x;            // 0..255
    const int dir   = chain >> 7;
    const int b     = chain & 127;
    float* orow = hbuf + (size_t)dir * NELEM + (size_t)b * (SEQ * NW);

    __shared__ __align__(16) float  cl[SEQ * 12];   // 24 KB cos/sin(x)
    __shared__ __align__(16) float  zb[SEQ * NW];   // 12 KB output buffer
    __shared__ float2 pY[2][4][DIM];                // ping-pong partials, 4 KB
    __shared__ __align__(16) float  mR[12];         // measure-sum slab
    __shared__ int cnt;

    const bool bf = detect_bf16(ang, &cnt);

    // ---- convert this chain's 3072 angles -> cl (cos,sin interleaved) ----
    {
        const int abase = b * (SEQ * NW);
#pragma unroll
        for (int k = 0; k < 12; ++k) {
            const int i = tid + k * 256;
            const float x = ldf(ang, abase + i, bf);
            float s, c;
            __sincosf(x, &s, &c);
            cl[2 * i]     = c;
            cl[2 * i + 1] = s;
        }
    }

    // ---- my 16 resident M columns: row = lane, cols = 16wv..16wv+15 ----
    v2f Mres[16];
    {
        const float2* mr2 =
            (const float2*)(Mg + (size_t)(dir * 64 + lane) * 128 + 32 * wv);
#pragma unroll
        for (int k = 0; k < 16; ++k) Mres[k] = (v2f){mr2[k].x, mr2[k].y};
    }

    // ---- my measurement assignment: 3 wires, Z or X ----
    const int w0  = (wv & 1) * 3;            // wire base
    const int isX = wv >> 1;                 // waves 2,3 do <X>
    int zmask3[3];
#pragma unroll
    for (int k = 0; k < 3; ++k)
        zmask3[k] = ((lane >> (5 - (w0 + k))) & 1) << 31;
    const int bpa32 = (lane ^ 32) << 2;      // mask-32 bpermute addr
    const int ow0 = wv ^ 1, ow1 = wv ^ 2, ow2 = wv ^ 3;   // other waves

    float h[6] = {0.f, 0.f, 0.f, 0.f, 0.f, 0.f};

    // encode h -> my 16-col matvec partial (registers only)
    auto encode_matvec = [&](v2f& acc) {
        float cw6[6], sw6[6];
#pragma unroll
        for (int w = 0; w < 6; ++w) sincos_half(h[w], sw6[w], cw6[w]);
        const float t0 = (wv & 2) ? sw6[0] : cw6[0];   // wire0 bit = wv>>1
        const float t1 = (wv & 1) ? sw6[1] : cw6[1];   // wire1 bit = wv&1
        const float A  = t0 * t1;
        float GH[4], GL[4];
        GH[0] = cw6[2] * cw6[3]; GH[1] = cw6[2] * sw6[3];
        GH[2] = sw6[2] * cw6[3]; GH[3] = sw6[2] * sw6[3];
#pragma unroll
        for (int a = 0; a < 4; ++a) GH[a] *= A;
        GL[0] = cw6[4] * cw6[5]; GL[1] = cw6[4] * sw6[5];
        GL[2] = sw6[4] * cw6[5]; GL[3] = sw6[4] * sw6[5];
        v2f y = {0.f, 0.f};
#pragma unroll
        for (int a = 0; a < 4; ++a) {
            v2f T = {0.f, 0.f};
#pragma unroll
            for (int b2 = 0; b2 < 4; ++b2)
                T = pkfma(GL[b2], Mres[4 * a + b2], T);
            y = pkfma(GH[a], T, y);
        }
        acc = y;
    };

    // walking pointers
    const float* cp = cl + (dir ? (SEQ - 1) * 12 : 0);
    const int   cstep = dir ? -12 : 12;
    float*       zp = zb + (dir ? (SEQ - 1) * NW : 0);
    const int   zstep = dir ? -NW : NW;

    __syncthreads();                         // cl staging + Mres visible

    // ---- peel: partial for the t=0 state (h = 0) ----
    v2f myacc;
    encode_matvec(myacc);
    pY[0][wv][lane] = (float2){myacc.x, myacc.y};
    __syncthreads();                         // barrier A

    for (int t = 0; t < SEQ; ++t) {
        const int buf = t & 1;

        // one batched LDS window: 3 partner partials + this step's cos/sin
        const float2 yA = pY[buf][ow0][lane];
        const float2 yB = pY[buf][ow1][lane];
        const float2 yC = pY[buf][ow2][lane];
        const float4 xq0 = ((const float4*)cp)[0];
        const float4 xq1 = ((const float4*)cp)[1];
        const float4 xq2 = ((const float4*)cp)[2];
        cp += cstep;

        const float yr = (myacc.x + yA.x) + (yB.x + yC.x);
        const float yi = (myacc.y + yA.y) + (yB.y + yC.y);

        // my 3 reductions (wave-uniform branches)
        float v3[3];
        if (isX) {
            float pr[3], pi[3];
            if (w0 == 0) {                   // masks 32,16,8
                pr[0] = __int_as_float(__builtin_amdgcn_ds_bpermute(
                            bpa32, __float_as_int(yr)));
                pi[0] = __int_as_float(__builtin_amdgcn_ds_bpermute(
                            bpa32, __float_as_int(yi)));
                pr[1] = swz<0x401F>(yr);     // XOR 16
                pi[1] = swz<0x401F>(yi);
                pr[2] = dpp_mov<0x128>(yr);  // row_ror:8 == XOR 8
                pi[2] = dpp_mov<0x128>(yi);
            } else {                         // masks 4,2,1
                pr[0] = swz<0x101F>(yr);     // XOR 4
                pi[0] = swz<0x101F>(yi);
                pr[1] = dpp_mov<0x4E>(yr);   // quad_perm [2,3,0,1] == XOR 2
                pi[1] = dpp_mov<0x4E>(yi);
                pr[2] = dpp_mov<0xB1>(yr);   // quad_perm [1,0,3,2] == XOR 1
                pi[2] = dpp_mov<0xB1>(yi);
            }
#pragma unroll
            for (int k = 0; k < 3; ++k) v3[k] = yr * pr[k] + yi * pi[k];
        } else {
            const float q = yr * yr + yi * yi;
#pragma unroll
            for (int k = 0; k < 3; ++k)
                v3[k] = __int_as_float(__float_as_int(q) ^ zmask3[k]);
        }
        red_stage3<0x111>(v3);   // row_shr:1
        red_stage3<0x112>(v3);   // row_shr:2
        red_stage3<0x114>(v3);   // row_shr:4
        red_stage3<0x118>(v3);   // row_shr:8
        red_stage3<0x142>(v3);   // row_bcast:15
        red_stage3<0x143>(v3);   // row_bcast:31

        if (lane == 63) {
            mR[wv * 3 + 0] = v3[0];
            mR[wv * 3 + 1] = v3[1];
            mR[wv * 3 + 2] = v3[2];
        }
        __syncthreads();                     // barrier B

        // slab read is the only post-B LDS dependency
        const float4 m0 = ((const float4*)mR)[0];   // Z0 Z1 Z2 Z3
        const float4 m1 = ((const float4*)mR)[1];   // Z4 Z5 X0 X1
        const float4 m2 = ((const float4*)mR)[2];   // X2 X3 X4 X5

        float z[6];
        z[0] = xq0.x * m0.x - xq0.y * m1.z;
        z[1] = xq0.z * m0.y - xq0.w * m1.w;
        z[2] = xq1.x * m0.z - xq1.y * m2.x;
        z[3] = xq1.z * m0.w - xq1.w * m2.y;
        z[4] = xq2.x * m1.x - xq2.y * m2.z;
        z[5] = xq2.z * m1.y - xq2.w * m2.w;

        if (tid == 63) {                     // one lane buffers outputs
#pragma unroll
            for (int w = 0; w < 6; ++w) zp[w] = z[w];
        }
        zp += zstep;
#pragma unroll
        for (int w = 0; w < 6; ++w) h[w] = z[w];   // h stays in VGPRs

        // next state's partial into the other buffer
        encode_matvec(myacc);
        pY[buf ^ 1][wv][lane] = (float2){myacc.x, myacc.y};
        __syncthreads();                     // barrier A
    }

    // ---- bulk store outputs: 768 float4 over 256 threads ----
    {
        const float4* zs4 = (const float4*)zb;
        float4* go = (float4*)orow;
#pragma unroll
        for (int k = 0; k < 3; ++k) {
            const int idx = tid + k * 256;
            go[idx] = zs4[idx];
        }
    }
}

// ---------------------------------------------------------------------------
// Kernel 3: out = sigmoid(fc)*h_fwd + sigmoid(bc)*h_bwd. Self-detects dtype.
// ---------------------------------------------------------------------------
__global__ void k_combine(const float* __restrict__ hbuf,
                          const void* __restrict__ ang,
                          const void* __restrict__ fc,
                          const void* __restrict__ bc,
                          void* __restrict__ out) {
    __shared__ int cnt;
    const bool bf = detect_bf16(ang, &cnt);
    const int i = blockIdx.x * blockDim.x + threadIdx.x;   // grid == NELEM
    const float sf = 1.f / (1.f + __expf(-ldf(fc, 0, bf)));
    const float sb = 1.f / (1.f + __expf(-ldf(bc, 0, bf)));
    const float v = sf * hbuf[i] + sb * hbuf[NELEM + i];
    if (bf) ((__hip_bfloat16*)out)[i] = __float2bfloat16(v);
    else    ((float*)out)[i] = v;
}

// ---------------------------------------------------------------------------
extern "C" void kernel_launch(void* const* d_in, const int* in_sizes, int n_in,
                              void* d_out, int out_size, void* d_ws, size_t ws_size,
                              hipStream_t stream) {
    const void* ang  = d_in[0];
    const void* poly = d_in[1];
    const void* fp   = d_in[2];
    const void* bp   = d_in[3];
    const void* fc   = d_in[4];
    const void* bc   = d_in[5];

    // ws (floats): hbuf[2*NELEM] | Mg[16384]
    float* hbuf = (float*)d_ws;
    float* Mg   = hbuf + 2 * NELEM;

    k_msetup<<<32, 256, 0, stream>>>(ang, poly, fp, bp, Mg);
    k_sim<<<256, 256, 0, stream>>>(ang, Mg, hbuf);
    k_combine<<<NELEM / 256, 256, 0, stream>>>(hbuf, ang, fc, bc, d_out);
}